// Round 22
// baseline (160.218 us; speedup 1.0000x reference)
//
#include <hip/hip_runtime.h>
#include <stdint.h>
#include <stddef.h>

#define DEV static __device__ __forceinline__

typedef float f32x4 __attribute__((ext_vector_type(4)));
typedef float f32x16 __attribute__((ext_vector_type(16)));
typedef unsigned u32x4 __attribute__((ext_vector_type(4)));
typedef __bf16 bf16x8 __attribute__((ext_vector_type(8)));

// Round-to-nearest-even f32 -> bf16 (as raw short). No NaN handling (inputs finite).
DEV short f2bf(float f) {
  union { float f; unsigned u; } a; a.f = f;
  unsigned r = a.u + 0x7fffu + ((a.u >> 16) & 1u);
  return (short)(r >> 16);
}

DEV void gld_lds16(const void* g, void* lds) {
  __builtin_amdgcn_global_load_lds(
      (__attribute__((address_space(1))) void*)(void*)g,
      (__attribute__((address_space(3))) void*)lds, 16, 0, 0);
}

DEV f32x4 MFMA(bf16x8 a, bf16x8 b, f32x4 c) {
  return __builtin_amdgcn_mfma_f32_16x16x32_bf16(a, b, c, 0, 0, 0);
}
DEV f32x16 MFMA32(bf16x8 a, bf16x8 b, f32x16 c) {
  return __builtin_amdgcn_mfma_f32_32x32x16_bf16(a, b, c, 0, 0, 0);
}

DEV float ex2(float x) { return __builtin_amdgcn_exp2f(x); }

// pack 2 f32 -> u32 of 2 bf16 (RNE)
DEV unsigned cvtpk(float lo, float hi) {
  unsigned r;
  asm("v_cvt_pk_bf16_f32 %0, %1, %2" : "=v"(r) : "v"(lo), "v"(hi));
  return r;
}

// cross-half (lane ^ 32) sum via permlane32_swap on copies
DEV float xhalf_sum(float v) {
  float a = v, b = v;
  asm volatile("v_permlane32_swap_b32 %0, %1" : "+v"(a), "+v"(b));
  return a + b;
}

#define LOG2E 1.4426950408889634f

// ---------------------------------------------------------------------------
// Constants: B=2, S=2048, D=1024, H=16, DK=64, M=B*S=4096
// Softmax uses FIXED m=0 (scores are LN-bounded; exp2 overflow-safe).
// ---------------------------------------------------------------------------

// 1+2) Fused: blocks 0..4095 convert weights f32->bf16; blocks 4096..8191 do
//      LayerNorm (one block per row).
__global__ __launch_bounds__(256) void k_cvtw_ln(
    const float* __restrict__ w0, const float* __restrict__ w1,
    const float* __restrict__ w2, const float* __restrict__ w3,
    short* __restrict__ dst, const float* __restrict__ x,
    const float* __restrict__ g, const float* __restrict__ be,
    short* __restrict__ xn) {
  __shared__ float ps[4], pss[4];
  if (blockIdx.x < 4096) {
    int i = blockIdx.x * 256 + threadIdx.x;           // 1M threads, 4 elems each
    int sel = i >> 18;                                // 2^18 threads per matrix
    const float* src = sel == 0 ? w0 : sel == 1 ? w1 : sel == 2 ? w2 : w3;
    int off = (i & 0x3ffff) * 4;
    float4 v = *(const float4*)(src + off);
    short4 o4; o4.x = f2bf(v.x); o4.y = f2bf(v.y); o4.z = f2bf(v.z); o4.w = f2bf(v.w);
    *(short4*)(dst + (size_t)i * 4) = o4;
  } else {
    int row = blockIdx.x - 4096;
    int t = threadIdx.x;
    const float4* xr = (const float4*)(x + (size_t)row * 1024);
    float4 v = xr[t];
    float s = v.x + v.y + v.z + v.w;
    float ss = v.x * v.x + v.y * v.y + v.z * v.z + v.w * v.w;
#pragma unroll
    for (int o = 32; o; o >>= 1) { s += __shfl_down(s, o); ss += __shfl_down(ss, o); }
    int w = t >> 6, lane = t & 63;
    if (lane == 0) { ps[w] = s; pss[w] = ss; }
    __syncthreads();
    float st = ps[0] + ps[1] + ps[2] + ps[3];
    float sst = pss[0] + pss[1] + pss[2] + pss[3];
    float mean = st * (1.0f / 1024.0f);
    float var = sst * (1.0f / 1024.0f) - mean * mean;
    float rstd = rsqrtf(var + 1e-5f);
    float4 gv = ((const float4*)g)[t];
    float4 bv = ((const float4*)be)[t];
    short4 o4;
    o4.x = f2bf((v.x - mean) * rstd * gv.x + bv.x);
    o4.y = f2bf((v.y - mean) * rstd * gv.y + bv.y);
    o4.z = f2bf((v.z - mean) * rstd * gv.z + bv.z);
    o4.w = f2bf((v.w - mean) * rstd * gv.w + bv.w);
    ((short4*)(xn + (size_t)row * 1024))[t] = o4;
  }
}

// 3) QKV projection GEMM — 256x256 tile, 8 waves (512 thr), BK=32,
//    A/B 3-slot LDS ring (96 KiB), depth-1 prefetch, ONE barrier + vmcnt(4)
//    per K-step, XOR-swizzled 64B rows. z==2 (V) writes V^T directly via an
//    LDS-transpose epilogue (k_trv fused away; each wave's 64-col span is
//    exactly one head). Grid (4,16,3). Q pre-scaled by 0.125*log2(e).
__global__ __launch_bounds__(512, 1) void k_gemm_qkv(
    const short* __restrict__ xn, const short* __restrict__ wbf,
    const float* __restrict__ bq, const float* __restrict__ bk,
    const float* __restrict__ bv, short* __restrict__ q_ws,
    short* __restrict__ k_ws, short* __restrict__ vt_ws) {
  __shared__ __align__(16) short lds[3][16384];   // slot: A[8192] | B[8192]
  int t = threadIdx.x, lane = t & 63, w = t >> 6;
  int wr = w >> 2, wc = w & 3;                    // wave tile: 128 rows x 64 cols
  int z = blockIdx.z;
  int row0 = blockIdx.y * 256, col0 = blockIdx.x * 256;
  const short* A = xn + (size_t)row0 * 1024;
  const short* Bw = wbf + (size_t)z * (1024 * 1024) + (size_t)col0 * 1024;

  // hoisted staging base pointers: chunk c (0..1023): row r=c>>2, j=(c&3)^(r&3)
  const short *ap0, *ap1, *bp0, *bp1;
  {
    int c = t, r = c >> 2, j = (c & 3) ^ (r & 3);
    ap0 = A + (size_t)r * 1024 + j * 8;
    bp0 = Bw + (size_t)r * 1024 + j * 8;
  }
  {
    int c = t + 512, r = c >> 2, j = (c & 3) ^ (r & 3);
    ap1 = A + (size_t)r * 1024 + j * 8;
    bp1 = Bw + (size_t)r * 1024 + j * 8;
  }

  // stage K-step s_ into slot s_%3 (4 loads/thread: 2 A + 2 B)
#define STGG(s_)                                                     \
  {                                                                  \
    short* at_ = lds[(s_) % 3];                                      \
    short* bt_ = lds[(s_) % 3] + 8192;                               \
    gld_lds16(ap0 + (s_) * 32, &at_[t * 8]);                         \
    gld_lds16(ap1 + (s_) * 32, &at_[(t + 512) * 8]);                 \
    gld_lds16(bp0 + (s_) * 32, &bt_[t * 8]);                         \
    gld_lds16(bp1 + (s_) * 32, &bt_[(t + 512) * 8]);                 \
  }

  // loop-invariant swizzled fragment element offsets
  int aoff[8], boff[4];
#pragma unroll
  for (int mi = 0; mi < 8; mi++) {
    int row = wr * 128 + mi * 16 + (lane & 15);
    aoff[mi] = row * 32 + (((lane >> 4) ^ (row & 3)) * 8);
  }
#pragma unroll
  for (int ni = 0; ni < 4; ni++) {
    int row = wc * 64 + ni * 16 + (lane & 15);
    boff[ni] = row * 32 + (((lane >> 4) ^ (row & 3)) * 8);
  }

  f32x4 acc[8][4];
#pragma unroll
  for (int m = 0; m < 8; m++)
#pragma unroll
    for (int n = 0; n < 4; n++) acc[m][n] = (f32x4)0.0f;

  STGG(0);
  for (int s = 0; s < 32; ++s) {
    STGG(s + 1 <= 31 ? s + 1 : 31);                  // tail re-issue (benign)
    asm volatile("s_waitcnt vmcnt(4)" ::: "memory"); // stage(s) landed (mine)
    __builtin_amdgcn_s_barrier();                    // all waves' stage(s)

    const short* at = lds[s % 3];
    const short* bt = lds[s % 3] + 8192;
    bf16x8 af[8], bf[4];
#pragma unroll
    for (int m = 0; m < 8; m++) af[m] = *(const bf16x8*)&at[aoff[m]];
#pragma unroll
    for (int n = 0; n < 4; n++) bf[n] = *(const bf16x8*)&bt[boff[n]];
    __builtin_amdgcn_s_setprio(1);
#pragma unroll
    for (int m = 0; m < 8; m++)
#pragma unroll
      for (int n = 0; n < 4; n++) acc[m][n] = MFMA(af[m], bf[n], acc[m][n]);
    __builtin_amdgcn_s_setprio(0);
    // no end barrier: writes at skew<=1 target slots (s+1)%3/(s+2)%3 != s%3.
  }

  if (z < 2) {
    const float* bias = z == 0 ? bq : bk;
    short* dst = z == 0 ? q_ws : k_ws;
    float scal = z == 0 ? (0.125f * LOG2E) : 1.0f;
#pragma unroll
    for (int m = 0; m < 8; m++)
#pragma unroll
      for (int n = 0; n < 4; n++)
#pragma unroll
        for (int r = 0; r < 4; r++) {
          int grow = row0 + wr * 128 + m * 16 + (lane >> 4) * 4 + r;  // b*2048+s
          int gcol = col0 + wc * 64 + n * 16 + (lane & 15);           // h*64+d
          float val = (acc[m][n][r] + bias[gcol]) * scal;
          int bb = grow >> 11, sr = grow & 2047, h = gcol >> 6, d = gcol & 63;
          dst[(((size_t)bb * 16 + h) * 2048 + sr) * 64 + d] = f2bf(val);
        }
  } else {
    // V: transpose epilogue -> vt_ws (bh, d, s). Wave (wr,wc): rows
    // wr*128..+127 (s), cols = head (col0>>6)+wc, d = n*16+(lane&15).
    // Two wr-passes through tb[4 heads][64 d][136 stride] (69.6 KiB).
    asm volatile("s_waitcnt vmcnt(0)" ::: "memory");   // drain ring prefetch
    __syncthreads();
    short* tb = &lds[0][0];
    int bb = row0 >> 11, s0 = row0 & 2047;
#pragma unroll
    for (int p = 0; p < 2; p++) {
      if (wr == p) {
#pragma unroll
        for (int m = 0; m < 8; m++)
#pragma unroll
          for (int n = 0; n < 4; n++)
#pragma unroll
            for (int r = 0; r < 4; r++) {
              int sl = m * 16 + (lane >> 4) * 4 + r;       // 0..127 local s
              int d = n * 16 + (lane & 15);
              int gcol = col0 + wc * 64 + d;
              tb[wc * 8704 + d * 136 + sl] = f2bf(acc[m][n][r] + bv[gcol]);
            }
      }
      __syncthreads();
      // cooperative store: 4096 chunks of 8 shorts (4 heads x 64 d x 16)
#pragma unroll
      for (int i = 0; i < 8; i++) {
        int c = t + i * 512;                      // 0..4095
        int hh = c >> 10, d = (c >> 4) & 63, sc = (c & 15) * 8;
        bf16x8 vv = *(const bf16x8*)&tb[hh * 8704 + d * 136 + sc];
        int bh = bb * 16 + (col0 >> 6) + hh;
        *(bf16x8*)&vt_ws[((size_t)bh * 64 + d) * 2048 + s0 + p * 128 + sc] = vv;
      }
      __syncthreads();
    }
  }
}

// 5) Flash attention pass 1 — swapped-operand 32x32x16, softmax||PV pipeline,
//    depth-2 prefetch, K 4-ring + V 5-ring => ONE barrier per iteration.
//    FIXED m=0. XCD-chunked block remap. Grid (16,16,2), 4 waves x 32 q-rows.
__global__ __launch_bounds__(256, 2) void k_attn1(
    const short* __restrict__ q_ws, const short* __restrict__ k_ws,
    const short* __restrict__ vt_ws, short* __restrict__ o_ws,
    float* __restrict__ l_ws) {
  __shared__ __align__(16) short k_lds[4][64 * 64];    // 4 x 8 KiB
  __shared__ __align__(16) short vt_lds[5][64 * 64];   // 5 x 8 KiB (72 KiB total)
  int t = threadIdx.x, lane = t & 63, w = t >> 6;
  int hi = lane >> 5, l31 = lane & 31;
  int flat = blockIdx.x + 16 * blockIdx.y + 256 * blockIdx.z;   // 0..511
  int mm = (flat & 7) * 64 + (flat >> 3);                       // XCD-chunked
  int qt = mm & 15, hd = (mm >> 4) & 15, b = mm >> 8;
  int bh = b * 16 + hd;
  int q0 = qt * 128;
  const short* qb = q_ws + (size_t)bh * (2048 * 64);
  const short* kb = k_ws + (size_t)bh * (2048 * 64);
  const short* vtb = vt_ws + (size_t)bh * (64 * 2048);
  int qg = q0 + w * 32 + l31;   // this lane's q row

  // Q B-fragments: col=q=lane&31, k-dim = d contiguous 8 at d4*16 + hi*8
  bf16x8 qf[4];
#pragma unroll
  for (int d4 = 0; d4 < 4; d4++)
    qf[d4] = *(const bf16x8*)&qb[(size_t)qg * 64 + d4 * 16 + hi * 8];
  asm volatile("s_waitcnt vmcnt(0)" ::: "memory");

  // hoisted per-lane staging base pointers (chunk c: row r=c>>3, swz j=(c&7)^(r&7))
  const short *kp0, *kp1, *vp0, *vp1;
  {
    int c = t, r = c >> 3, j = (c & 7) ^ (r & 7);
    kp0 = kb + (size_t)r * 64 + j * 8;
    vp0 = vtb + (size_t)r * 2048 + j * 8;
  }
  {
    int c = t + 256, r = c >> 3, j = (c & 7) ^ (r & 7);
    kp1 = kb + (size_t)r * 64 + j * 8;
    vp1 = vtb + (size_t)r * 2048 + j * 8;
  }

  // Loop-invariant swizzled LDS fragment offsets (element index within a tile).
  int koff[8];
#pragma unroll
  for (int d4 = 0; d4 < 4; d4++) {
    int row0 = l31, row1 = 32 + l31;
    koff[2 * d4]     = row0 * 64 + (((d4 * 2 + hi) ^ (row0 & 7)) * 8);
    koff[2 * d4 + 1] = row1 * 64 + (((d4 * 2 + hi) ^ (row1 & 7)) * 8);
  }

  // One tile = 4 load instrs/thread (2 K + 2 V). Slots indexed by TILE number.
#define STG(tl_)                                                         \
  {                                                                      \
    gld_lds16(kp0 + (size_t)(tl_) * 4096, &k_lds[(tl_) & 3][t * 8]);     \
    gld_lds16(kp1 + (size_t)(tl_) * 4096, &k_lds[(tl_) & 3][(t + 256) * 8]); \
    gld_lds16(vp0 + (size_t)(tl_) * 64, &vt_lds[(tl_) % 5][t * 8]);      \
    gld_lds16(vp1 + (size_t)(tl_) * 64, &vt_lds[(tl_) % 5][(t + 256) * 8]); \
  }

  STG(0);
  STG(1);          // 8 instrs outstanding

  f32x16 Oacc[2];
#pragma unroll
  for (int i = 0; i < 16; i++) { Oacc[0][i] = 0.0f; Oacc[1][i] = 0.0f; }
  float lrun = 0.0f;
  bf16x8 pb[4];   // P fragments of the PREVIOUS iteration

  for (int it = 0; it < 32; ++it) {
    int tn = it + 2 <= 31 ? it + 2 : 31;   // tail re-issues tile 31 (same data)
    STG(tn);
    asm volatile("s_waitcnt vmcnt(8)" ::: "memory");   // tile(it) fully landed
    __builtin_amdgcn_s_barrier();                      // sole barrier this iter

    const short* kl = k_lds[it & 3];
    const short* vl = vt_lds[(it + 4) % 5];            // V(it-1)

    // Batch-load ALL fragments (reads pipeline in the LDS unit).
    bf16x8 kfr[8], vfr[8];
#pragma unroll
    for (int i = 0; i < 8; i++) kfr[i] = *(const bf16x8*)&kl[koff[i]];
#pragma unroll
    for (int i = 0; i < 8; i++) vfr[i] = *(const bf16x8*)&vl[koff[i]];

    __builtin_amdgcn_s_setprio(1);
    // S^T = K @ Q^T : lane q = l31
    f32x16 S0 = (f32x16)0.0f, S1 = (f32x16)0.0f;
#pragma unroll
    for (int d4 = 0; d4 < 4; d4++) {
      S0 = MFMA32(kfr[2 * d4], qf[d4], S0);
      S1 = MFMA32(kfr[2 * d4 + 1], qf[d4], S1);
    }
    // O^T += V^T(it-1) @ P(it-1): MFMA pipe, overlaps softmax VALU below
    if (it) {
#pragma unroll
      for (int ks = 0; ks < 4; ks++) {
        Oacc[0] = MFMA32(vfr[2 * ks], pb[ks], Oacc[0]);
        Oacc[1] = MFMA32(vfr[2 * ks + 1], pb[ks], Oacc[1]);
      }
    }
    __builtin_amdgcn_s_setprio(0);

    // softmax(it) with fixed m=0: P = exp2(S), row sum
    float rs0 = 0.0f, rs1 = 0.0f;
#pragma unroll
    for (int i = 0; i < 16; i++) {
      float p0 = ex2(S0[i]);
      float p1 = ex2(S1[i]);
      S0[i] = p0; S1[i] = p1;
      rs0 += p0; rs1 += p1;
    }
    lrun += xhalf_sum(rs0 + rs1);

    // pack P(it) -> pb[0..3] (in-register, no LDS)
#pragma unroll
    for (int ks = 0; ks < 4; ks++) {
      unsigned wA, wB, wC, wD;
      if (ks == 0) {
        wA = cvtpk(S0[0], S0[1]);  wB = cvtpk(S0[2], S0[3]);
        wC = cvtpk(S0[4], S0[5]);  wD = cvtpk(S0[6], S0[7]);
      } else if (ks == 1) {
        wA = cvtpk(S0[8], S0[9]);  wB = cvtpk(S0[10], S0[11]);
        wC = cvtpk(S0[12], S0[13]); wD = cvtpk(S0[14], S0[15]);
      } else if (ks == 2) {
        wA = cvtpk(S1[0], S1[1]);  wB = cvtpk(S1[2], S1[3]);
        wC = cvtpk(S1[4], S1[5]);  wD = cvtpk(S1[6], S1[7]);
      } else {
        wA = cvtpk(S1[8], S1[9]);  wB = cvtpk(S1[10], S1[11]);
        wC = cvtpk(S1[12], S1[13]); wD = cvtpk(S1[14], S1[15]);
      }
      asm volatile("v_permlane32_swap_b32 %0, %1" : "+v"(wA), "+v"(wC));
      asm volatile("v_permlane32_swap_b32 %0, %1" : "+v"(wB), "+v"(wD));
      u32x4 uu; uu.x = wA; uu.y = wB; uu.z = wC; uu.w = wD;
      pb[ks] = __builtin_bit_cast(bf16x8, uu);
    }
    // no end-of-iteration barrier: ring depths (K=4, V=5) make writes at
    // wave-skew<=1 land in slots disjoint from any concurrent reads.
  }
  asm volatile("s_waitcnt vmcnt(0)" ::: "memory");   // drain trailing prefetch
  __builtin_amdgcn_s_barrier();

  // final PV(31): tile 31 -> slot 31 % 5 == 1
  {
    const short* vl = vt_lds[1];
    __builtin_amdgcn_s_setprio(1);
#pragma unroll
    for (int ks = 0; ks < 4; ks++) {
      Oacc[0] = MFMA32(*(const bf16x8*)&vl[koff[2 * ks]], pb[ks], Oacc[0]);
      Oacc[1] = MFMA32(*(const bf16x8*)&vl[koff[2 * ks + 1]], pb[ks], Oacc[1]);
    }
    __builtin_amdgcn_s_setprio(0);
  }

  float rl = 1.0f / lrun;
  if (lane < 32) {
    l_ws[bh * 2048 + qg] = rl;
  }
  // O write: lane holds q=l31, d = dt*32 + g*8 + hi*4 + e  (e contiguous)
#pragma unroll
  for (int dt = 0; dt < 2; dt++)
#pragma unroll
    for (int g = 0; g < 4; g++) {
      short4 o4;
      o4.x = f2bf(Oacc[dt][g * 4 + 0] * rl);
      o4.y = f2bf(Oacc[dt][g * 4 + 1] * rl);
      o4.z = f2bf(Oacc[dt][g * 4 + 2] * rl);
      o4.w = f2bf(Oacc[dt][g * 4 + 3] * rl);
      int d = dt * 32 + g * 8 + hi * 4;
      *(short4*)&o_ws[((size_t)(b * 2048 + qg)) * 1024 + hd * 64 + d] = o4;
    }
}

// 6+7) TAIL: gemm_out (blocks 0..255) || attn2 (blocks 256..767, QBLK=128:
//      each wave 32 q-rows = 2 m-groups sharing each K-fragment read).
__global__ __launch_bounds__(256, 1) void k_tail(
    const short* __restrict__ q_ws, const short* __restrict__ k_ws,
    const float* __restrict__ l_ws, float* __restrict__ out1,
    const short* __restrict__ o_ws, const short* __restrict__ wo_bf,
    const float* __restrict__ bo, const float* __restrict__ x,
    float* __restrict__ out0) {
  __shared__ __align__(16) char smem[3 * 16384 + 3 * 512];  // 50.7 KiB union
  int t = threadIdx.x, lane = t & 63, w = t >> 6;

  if (blockIdx.x < 256) {
    // ---- Output projection + bias + residual (f32 out). BK=32. ----
    short* at = (short*)smem;
    short* bt = (short*)(smem + 8192);
    int wr = w >> 1, wc = w & 1;
    int fo = blockIdx.x;
    int col0 = (fo & 7) * 128, row0 = (fo >> 3) * 128;
    const short* A = o_ws + (size_t)row0 * 1024;
    const short* Bw = wo_bf + (size_t)col0 * 1024;
    f32x4 acc[4][4];
#pragma unroll
    for (int m = 0; m < 4; m++)
#pragma unroll
      for (int n = 0; n < 4; n++) acc[m][n] = (f32x4)0.0f;

    for (int k0 = 0; k0 < 1024; k0 += 32) {
#pragma unroll
      for (int i = 0; i < 2; i++) {
        int c = t + i * 256;
        int r = c >> 2, cc = (c & 3) * 8;
        gld_lds16(A + (size_t)r * 1024 + k0 + cc, &at[c * 8]);
        gld_lds16(Bw + (size_t)r * 1024 + k0 + cc, &bt[c * 8]);
      }
      __syncthreads();
      bf16x8 af[4], bfr[4];
#pragma unroll
      for (int m = 0; m < 4; m++)
        af[m] = *(const bf16x8*)&at[(wr * 64 + m * 16 + (lane & 15)) * 32 + (lane >> 4) * 8];
#pragma unroll
      for (int n = 0; n < 4; n++)
        bfr[n] = *(const bf16x8*)&bt[(wc * 64 + n * 16 + (lane & 15)) * 32 + (lane >> 4) * 8];
#pragma unroll
      for (int m = 0; m < 4; m++)
#pragma unroll
        for (int n = 0; n < 4; n++) acc[m][n] = MFMA(af[m], bfr[n], acc[m][n]);
      __syncthreads();
    }
#pragma unroll
    for (int m = 0; m < 4; m++)
#pragma unroll
      for (int n = 0; n < 4; n++)
#pragma unroll
        for (int r = 0; r < 4; r++) {
          int grow = row0 + wr * 64 + m * 16 + (lane >> 4) * 4 + r;
          int gcol = col0 + wc * 64 + n * 16 + (lane & 15);
          float val = acc[m][n][r] + bo[gcol] + x[(size_t)grow * 1024 + gcol];
          out0[(size_t)grow * 1024 + gcol] = val;
        }
  } else {
    // ---- Mean attention: m=0, QBLK=128, K 3-ring, one barrier per head,
    //      Q-fragment register double-buffer. ----
    short* k_lds2 = (short*)smem;                       // 3 x 128*64 shorts
    float* l_lds = (float*)(smem + 49152);              // 3 x 128 floats
    int flat = blockIdx.x - 256;                        // 0..511
    int mm = (flat & 7) * 64 + (flat >> 3);             // XCD-chunked
    int q0 = (mm & 15) * 128, k2 = ((mm >> 4) & 15) * 128, b = mm >> 8;

    f32x4 pacc[2][8];
#pragma unroll
    for (int m = 0; m < 2; m++)
#pragma unroll
      for (int n = 0; n < 8; n++) pacc[m][n] = (f32x4)0.0f;

    int qrow0 = q0 + w * 32 + (lane & 15);              // m-group 0; +16 for 1
    size_t qoff0 = (size_t)qrow0 * 64 + (lane >> 4) * 8;  // kf adds 32
    const short* qb0 = q_ws + (size_t)(b * 16) * (2048 * 64);

#define STAGE2(hh)                                                               \
    {                                                                            \
      int bh_ = b * 16 + (hh);                                                   \
      const short* kb_ = k_ws + (size_t)bh_ * (2048 * 64);                       \
      short* kdst_ = k_lds2 + ((hh) % 3) * (128 * 64);                           \
      _Pragma("unroll")                                                          \
      for (int i = 0; i < 4; i++) {                                              \
        int c = t + i * 256;                                                     \
        int r = c >> 3, j = (c & 7) ^ (r & 7);                                   \
        gld_lds16(kb_ + (size_t)(k2 + r) * 64 + j * 8, &kdst_[c * 8]);           \
      }                                                                          \
      int cc = w * 8 + (t & 63);                                                 \
      if ((t & 63) < 8) {                                                        \
        gld_lds16(&l_ws[(size_t)bh_ * 2048 + q0 + cc * 4],                       \
                  &l_lds[((hh) % 3) * 128 + cc * 4]);                            \
      }                                                                          \
    }

    // Prologue: Q(0) (4 frags) into current regs; stage(0).
    bf16x8 qc00 = *(const bf16x8*)&qb0[qoff0];
    bf16x8 qc01 = *(const bf16x8*)&qb0[qoff0 + 32];
    bf16x8 qc10 = *(const bf16x8*)&qb0[qoff0 + 16 * 64];
    bf16x8 qc11 = *(const bf16x8*)&qb0[qoff0 + 16 * 64 + 32];
    STAGE2(0);
    bf16x8 qn00, qn01, qn10, qn11;
    for (int h = 0; h < 16; ++h) {
      int hn = h < 15 ? h + 1 : 15;
      STAGE2(hn);                                        // 4(+1) vm ops
      {
        size_t qb_h = (size_t)hn * (2048 * 64);
        qn00 = *(const bf16x8*)&qb0[qb_h + qoff0];
        qn01 = *(const bf16x8*)&qb0[qb_h + qoff0 + 32];
        qn10 = *(const bf16x8*)&qb0[qb_h + qoff0 + 16 * 64];
        qn11 = *(const bf16x8*)&qb0[qb_h + qoff0 + 16 * 64 + 32];
      }
      // Guarantee stage(h) retired (oldest 4/5 ops); Q regs compiler-fenced.
      asm volatile("s_waitcnt vmcnt(12)" ::: "memory");
      __builtin_amdgcn_s_barrier();

      const short* kl = k_lds2 + (h % 3) * (128 * 64);
      f32x4 sc0[8], sc1[8];
#pragma unroll
      for (int n = 0; n < 8; n++) { sc0[n] = (f32x4)0.0f; sc1[n] = (f32x4)0.0f; }
#pragma unroll
      for (int kf = 0; kf < 2; kf++)
#pragma unroll
        for (int n = 0; n < 8; n++) {
          int row = n * 16 + (lane & 15);
          bf16x8 kfr = *(const bf16x8*)&kl[row * 64 + (((kf * 4 + (lane >> 4)) ^ (row & 7)) * 8)];
          sc0[n] = MFMA(kf == 0 ? qc00 : qc01, kfr, sc0[n]);
          sc1[n] = MFMA(kf == 0 ? qc10 : qc11, kfr, sc1[n]);
        }
      f32x4 lh0 = *(const f32x4*)&l_lds[(h % 3) * 128 + w * 32 + (lane >> 4) * 4];
      f32x4 lh1 = *(const f32x4*)&l_lds[(h % 3) * 128 + w * 32 + 16 + (lane >> 4) * 4];
#pragma unroll
      for (int n = 0; n < 8; n++)
#pragma unroll
        for (int r = 0; r < 4; r++) {
          pacc[0][n][r] += ex2(sc0[n][r]) * lh0[r];
          pacc[1][n][r] += ex2(sc1[n][r]) * lh1[r];
        }
      qc00 = qn00; qc01 = qn01; qc10 = qn10; qc11 = qn11;
      // no end barrier: 3-ring write slot (h+2)%3 != read slot h%3 at skew<=1.
    }

#pragma unroll
    for (int m = 0; m < 2; m++)
#pragma unroll
      for (int n = 0; n < 8; n++)
#pragma unroll
        for (int r = 0; r < 4; r++) {
          int q = q0 + w * 32 + m * 16 + (lane >> 4) * 4 + r;
          int k = k2 + n * 16 + (lane & 15);
          out1[((size_t)b * 2048 + q) * 2048 + k] = pacc[m][n][r] * 0.0625f;
        }
  }
}

extern "C" void kernel_launch(void* const* d_in, const int* in_sizes, int n_in,
                              void* d_out, int out_size, void* d_ws, size_t ws_size,
                              hipStream_t stream) {
  (void)in_sizes; (void)n_in; (void)out_size; (void)ws_size;
  const float* x   = (const float*)d_in[0];
  const float* Wq  = (const float*)d_in[1];
  const float* bq  = (const float*)d_in[2];
  const float* Wk  = (const float*)d_in[3];
  const float* bk  = (const float*)d_in[4];
  const float* Wv  = (const float*)d_in[5];
  const float* bv  = (const float*)d_in[6];
  const float* Wo  = (const float*)d_in[7];
  const float* bo  = (const float*)d_in[8];
  const float* lng = (const float*)d_in[9];
  const float* lnb = (const float*)d_in[10];
  float* out0 = (float*)d_out;
  float* out1 = out0 + (size_t)2 * 2048 * 1024;

  char* ws = (char*)d_ws;
  short* xn    = (short*)(ws);                 // 8 MiB
  short* q_ws  = (short*)(ws + 8388608);       // 8 MiB
  short* k_ws  = (short*)(ws + 16777216);      // 8 MiB
  short* o_ws  = (short*)(ws + 25165824);      // 8 MiB (attention output O)
  short* vt_ws = (short*)(ws + 33554432);      // 8 MiB (V^T from QKV GEMM)
  short* wbf   = (short*)(ws + 41943040);      // 8 MiB (Wq,Wk,Wv,Wo bf16)
  float* l_ws  = (float*)(ws + 50331648);      // 256 KiB

  k_cvtw_ln<<<8192, 256, 0, stream>>>(Wq, Wk, Wv, Wo, wbf, x, lng, lnb, xn);
  k_gemm_qkv<<<dim3(4, 16, 3), 512, 0, stream>>>(xn, wbf, bq, bk, bv, q_ws, k_ws, vt_ws);
  k_attn1<<<dim3(16, 16, 2), 256, 0, stream>>>(q_ws, k_ws, vt_ws, o_ws, l_ws);
  k_tail<<<768, 256, 0, stream>>>(q_ws, k_ws, l_ws, out1,
                                  o_ws, wbf + (size_t)3 * 1024 * 1024, bo, x, out0);
}

// Round 23
// 153.638 us; speedup vs baseline: 1.0428x; 1.0428x over previous
//
#include <hip/hip_runtime.h>
#include <stdint.h>
#include <stddef.h>

#define DEV static __device__ __forceinline__

typedef float f32x4 __attribute__((ext_vector_type(4)));
typedef float f32x16 __attribute__((ext_vector_type(16)));
typedef unsigned u32x4 __attribute__((ext_vector_type(4)));
typedef __bf16 bf16x8 __attribute__((ext_vector_type(8)));

// Round-to-nearest-even f32 -> bf16 (as raw short). No NaN handling (inputs finite).
DEV short f2bf(float f) {
  union { float f; unsigned u; } a; a.f = f;
  unsigned r = a.u + 0x7fffu + ((a.u >> 16) & 1u);
  return (short)(r >> 16);
}

DEV void gld_lds16(const void* g, void* lds) {
  __builtin_amdgcn_global_load_lds(
      (__attribute__((address_space(1))) void*)(void*)g,
      (__attribute__((address_space(3))) void*)lds, 16, 0, 0);
}

DEV f32x4 MFMA(bf16x8 a, bf16x8 b, f32x4 c) {
  return __builtin_amdgcn_mfma_f32_16x16x32_bf16(a, b, c, 0, 0, 0);
}
DEV f32x16 MFMA32(bf16x8 a, bf16x8 b, f32x16 c) {
  return __builtin_amdgcn_mfma_f32_32x32x16_bf16(a, b, c, 0, 0, 0);
}

DEV float ex2(float x) { return __builtin_amdgcn_exp2f(x); }

// pack 2 f32 -> u32 of 2 bf16 (RNE)
DEV unsigned cvtpk(float lo, float hi) {
  unsigned r;
  asm("v_cvt_pk_bf16_f32 %0, %1, %2" : "=v"(r) : "v"(lo), "v"(hi));
  return r;
}

// cross-half (lane ^ 32) sum via permlane32_swap on copies
DEV float xhalf_sum(float v) {
  float a = v, b = v;
  asm volatile("v_permlane32_swap_b32 %0, %1" : "+v"(a), "+v"(b));
  return a + b;
}

#define LOG2E 1.4426950408889634f

// ---------------------------------------------------------------------------
// Constants: B=2, S=2048, D=1024, H=16, DK=64, M=B*S=4096
// Softmax uses FIXED m=0 (scores are LN-bounded; exp2 overflow-safe).
// ---------------------------------------------------------------------------

// 1+2) Fused: blocks 0..4095 convert weights f32->bf16; blocks 4096..8191 do
//      LayerNorm (one block per row).
__global__ __launch_bounds__(256) void k_cvtw_ln(
    const float* __restrict__ w0, const float* __restrict__ w1,
    const float* __restrict__ w2, const float* __restrict__ w3,
    short* __restrict__ dst, const float* __restrict__ x,
    const float* __restrict__ g, const float* __restrict__ be,
    short* __restrict__ xn) {
  __shared__ float ps[4], pss[4];
  if (blockIdx.x < 4096) {
    int i = blockIdx.x * 256 + threadIdx.x;           // 1M threads, 4 elems each
    int sel = i >> 18;                                // 2^18 threads per matrix
    const float* src = sel == 0 ? w0 : sel == 1 ? w1 : sel == 2 ? w2 : w3;
    int off = (i & 0x3ffff) * 4;
    float4 v = *(const float4*)(src + off);
    short4 o4; o4.x = f2bf(v.x); o4.y = f2bf(v.y); o4.z = f2bf(v.z); o4.w = f2bf(v.w);
    *(short4*)(dst + (size_t)i * 4) = o4;
  } else {
    int row = blockIdx.x - 4096;
    int t = threadIdx.x;
    const float4* xr = (const float4*)(x + (size_t)row * 1024);
    float4 v = xr[t];
    float s = v.x + v.y + v.z + v.w;
    float ss = v.x * v.x + v.y * v.y + v.z * v.z + v.w * v.w;
#pragma unroll
    for (int o = 32; o; o >>= 1) { s += __shfl_down(s, o); ss += __shfl_down(ss, o); }
    int w = t >> 6, lane = t & 63;
    if (lane == 0) { ps[w] = s; pss[w] = ss; }
    __syncthreads();
    float st = ps[0] + ps[1] + ps[2] + ps[3];
    float sst = pss[0] + pss[1] + pss[2] + pss[3];
    float mean = st * (1.0f / 1024.0f);
    float var = sst * (1.0f / 1024.0f) - mean * mean;
    float rstd = rsqrtf(var + 1e-5f);
    float4 gv = ((const float4*)g)[t];
    float4 bv = ((const float4*)be)[t];
    short4 o4;
    o4.x = f2bf((v.x - mean) * rstd * gv.x + bv.x);
    o4.y = f2bf((v.y - mean) * rstd * gv.y + bv.y);
    o4.z = f2bf((v.z - mean) * rstd * gv.z + bv.z);
    o4.w = f2bf((v.w - mean) * rstd * gv.w + bv.w);
    ((short4*)(xn + (size_t)row * 1024))[t] = o4;
  }
}

// 3) QKV projection GEMM — 256x256 tile, 8 waves (512 thr), BK=32,
//    A/B 3-slot LDS ring (96 KiB), depth-1 prefetch, ONE barrier + vmcnt(4)
//    per K-step, XOR-swizzled 64B rows. z==2 (V) writes V^T directly via an
//    LDS-transpose epilogue (k_trv fused away; each wave's 64-col span is
//    exactly one head). Grid (4,16,3). Q pre-scaled by 0.125*log2(e).
__global__ __launch_bounds__(512, 1) void k_gemm_qkv(
    const short* __restrict__ xn, const short* __restrict__ wbf,
    const float* __restrict__ bq, const float* __restrict__ bk,
    const float* __restrict__ bv, short* __restrict__ q_ws,
    short* __restrict__ k_ws, short* __restrict__ vt_ws) {
  __shared__ __align__(16) short lds[3][16384];   // slot: A[8192] | B[8192]
  int t = threadIdx.x, lane = t & 63, w = t >> 6;
  int wr = w >> 2, wc = w & 3;                    // wave tile: 128 rows x 64 cols
  int z = blockIdx.z;
  int row0 = blockIdx.y * 256, col0 = blockIdx.x * 256;
  const short* A = xn + (size_t)row0 * 1024;
  const short* Bw = wbf + (size_t)z * (1024 * 1024) + (size_t)col0 * 1024;

  // hoisted staging base pointers: chunk c (0..1023): row r=c>>2, j=(c&3)^(r&3)
  const short *ap0, *ap1, *bp0, *bp1;
  {
    int c = t, r = c >> 2, j = (c & 3) ^ (r & 3);
    ap0 = A + (size_t)r * 1024 + j * 8;
    bp0 = Bw + (size_t)r * 1024 + j * 8;
  }
  {
    int c = t + 512, r = c >> 2, j = (c & 3) ^ (r & 3);
    ap1 = A + (size_t)r * 1024 + j * 8;
    bp1 = Bw + (size_t)r * 1024 + j * 8;
  }

  // stage K-step s_ into slot s_%3 (4 loads/thread: 2 A + 2 B)
#define STGG(s_)                                                     \
  {                                                                  \
    short* at_ = lds[(s_) % 3];                                      \
    short* bt_ = lds[(s_) % 3] + 8192;                               \
    gld_lds16(ap0 + (s_) * 32, &at_[t * 8]);                         \
    gld_lds16(ap1 + (s_) * 32, &at_[(t + 512) * 8]);                 \
    gld_lds16(bp0 + (s_) * 32, &bt_[t * 8]);                         \
    gld_lds16(bp1 + (s_) * 32, &bt_[(t + 512) * 8]);                 \
  }

  // loop-invariant swizzled fragment element offsets
  int aoff[8], boff[4];
#pragma unroll
  for (int mi = 0; mi < 8; mi++) {
    int row = wr * 128 + mi * 16 + (lane & 15);
    aoff[mi] = row * 32 + (((lane >> 4) ^ (row & 3)) * 8);
  }
#pragma unroll
  for (int ni = 0; ni < 4; ni++) {
    int row = wc * 64 + ni * 16 + (lane & 15);
    boff[ni] = row * 32 + (((lane >> 4) ^ (row & 3)) * 8);
  }

  f32x4 acc[8][4];
#pragma unroll
  for (int m = 0; m < 8; m++)
#pragma unroll
    for (int n = 0; n < 4; n++) acc[m][n] = (f32x4)0.0f;

  STGG(0);
  for (int s = 0; s < 32; ++s) {
    STGG(s + 1 <= 31 ? s + 1 : 31);                  // tail re-issue (benign)
    asm volatile("s_waitcnt vmcnt(4)" ::: "memory"); // stage(s) landed (mine)
    __builtin_amdgcn_s_barrier();                    // all waves' stage(s)

    const short* at = lds[s % 3];
    const short* bt = lds[s % 3] + 8192;
    bf16x8 af[8], bf[4];
#pragma unroll
    for (int m = 0; m < 8; m++) af[m] = *(const bf16x8*)&at[aoff[m]];
#pragma unroll
    for (int n = 0; n < 4; n++) bf[n] = *(const bf16x8*)&bt[boff[n]];
    __builtin_amdgcn_s_setprio(1);
#pragma unroll
    for (int m = 0; m < 8; m++)
#pragma unroll
      for (int n = 0; n < 4; n++) acc[m][n] = MFMA(af[m], bf[n], acc[m][n]);
    __builtin_amdgcn_s_setprio(0);
    // no end barrier: writes at skew<=1 target slots (s+1)%3/(s+2)%3 != s%3.
  }

  if (z < 2) {
    const float* bias = z == 0 ? bq : bk;
    short* dst = z == 0 ? q_ws : k_ws;
    float scal = z == 0 ? (0.125f * LOG2E) : 1.0f;
#pragma unroll
    for (int m = 0; m < 8; m++)
#pragma unroll
      for (int n = 0; n < 4; n++)
#pragma unroll
        for (int r = 0; r < 4; r++) {
          int grow = row0 + wr * 128 + m * 16 + (lane >> 4) * 4 + r;  // b*2048+s
          int gcol = col0 + wc * 64 + n * 16 + (lane & 15);           // h*64+d
          float val = (acc[m][n][r] + bias[gcol]) * scal;
          int bb = grow >> 11, sr = grow & 2047, h = gcol >> 6, d = gcol & 63;
          dst[(((size_t)bb * 16 + h) * 2048 + sr) * 64 + d] = f2bf(val);
        }
  } else {
    // V: transpose epilogue -> vt_ws (bh, d, s). Wave (wr,wc): rows
    // wr*128..+127 (s), cols = head (col0>>6)+wc, d = n*16+(lane&15).
    // Two wr-passes through tb[4 heads][64 d][136 stride] (69.6 KiB).
    asm volatile("s_waitcnt vmcnt(0)" ::: "memory");   // drain ring prefetch
    __syncthreads();
    short* tb = &lds[0][0];
    int bb = row0 >> 11, s0 = row0 & 2047;
#pragma unroll
    for (int p = 0; p < 2; p++) {
      if (wr == p) {
#pragma unroll
        for (int m = 0; m < 8; m++)
#pragma unroll
          for (int n = 0; n < 4; n++)
#pragma unroll
            for (int r = 0; r < 4; r++) {
              int sl = m * 16 + (lane >> 4) * 4 + r;       // 0..127 local s
              int d = n * 16 + (lane & 15);
              int gcol = col0 + wc * 64 + d;
              tb[wc * 8704 + d * 136 + sl] = f2bf(acc[m][n][r] + bv[gcol]);
            }
      }
      __syncthreads();
      // cooperative store: 4096 chunks of 8 shorts (4 heads x 64 d x 16)
#pragma unroll
      for (int i = 0; i < 8; i++) {
        int c = t + i * 512;                      // 0..4095
        int hh = c >> 10, d = (c >> 4) & 63, sc = (c & 15) * 8;
        bf16x8 vv = *(const bf16x8*)&tb[hh * 8704 + d * 136 + sc];
        int bh = bb * 16 + (col0 >> 6) + hh;
        *(bf16x8*)&vt_ws[((size_t)bh * 64 + d) * 2048 + s0 + p * 128 + sc] = vv;
      }
      __syncthreads();
    }
  }
}

// 5) Flash attention pass 1 — swapped-operand 32x32x16, softmax||PV pipeline,
//    depth-2 prefetch, K 4-ring + V 5-ring => ONE barrier per iteration.
//    FIXED m=0. XCD-chunked block remap. Grid (16,16,2), 4 waves x 32 q-rows.
__global__ __launch_bounds__(256, 2) void k_attn1(
    const short* __restrict__ q_ws, const short* __restrict__ k_ws,
    const short* __restrict__ vt_ws, short* __restrict__ o_ws,
    float* __restrict__ l_ws) {
  __shared__ __align__(16) short k_lds[4][64 * 64];    // 4 x 8 KiB
  __shared__ __align__(16) short vt_lds[5][64 * 64];   // 5 x 8 KiB (72 KiB total)
  int t = threadIdx.x, lane = t & 63, w = t >> 6;
  int hi = lane >> 5, l31 = lane & 31;
  int flat = blockIdx.x + 16 * blockIdx.y + 256 * blockIdx.z;   // 0..511
  int mm = (flat & 7) * 64 + (flat >> 3);                       // XCD-chunked
  int qt = mm & 15, hd = (mm >> 4) & 15, b = mm >> 8;
  int bh = b * 16 + hd;
  int q0 = qt * 128;
  const short* qb = q_ws + (size_t)bh * (2048 * 64);
  const short* kb = k_ws + (size_t)bh * (2048 * 64);
  const short* vtb = vt_ws + (size_t)bh * (64 * 2048);
  int qg = q0 + w * 32 + l31;   // this lane's q row

  // Q B-fragments: col=q=lane&31, k-dim = d contiguous 8 at d4*16 + hi*8
  bf16x8 qf[4];
#pragma unroll
  for (int d4 = 0; d4 < 4; d4++)
    qf[d4] = *(const bf16x8*)&qb[(size_t)qg * 64 + d4 * 16 + hi * 8];
  asm volatile("s_waitcnt vmcnt(0)" ::: "memory");

  // hoisted per-lane staging base pointers (chunk c: row r=c>>3, swz j=(c&7)^(r&7))
  const short *kp0, *kp1, *vp0, *vp1;
  {
    int c = t, r = c >> 3, j = (c & 7) ^ (r & 7);
    kp0 = kb + (size_t)r * 64 + j * 8;
    vp0 = vtb + (size_t)r * 2048 + j * 8;
  }
  {
    int c = t + 256, r = c >> 3, j = (c & 7) ^ (r & 7);
    kp1 = kb + (size_t)r * 64 + j * 8;
    vp1 = vtb + (size_t)r * 2048 + j * 8;
  }

  // Loop-invariant swizzled LDS fragment offsets (element index within a tile).
  int koff[8];
#pragma unroll
  for (int d4 = 0; d4 < 4; d4++) {
    int row0 = l31, row1 = 32 + l31;
    koff[2 * d4]     = row0 * 64 + (((d4 * 2 + hi) ^ (row0 & 7)) * 8);
    koff[2 * d4 + 1] = row1 * 64 + (((d4 * 2 + hi) ^ (row1 & 7)) * 8);
  }

  // One tile = 4 load instrs/thread (2 K + 2 V). Slots indexed by TILE number.
#define STG(tl_)                                                         \
  {                                                                      \
    gld_lds16(kp0 + (size_t)(tl_) * 4096, &k_lds[(tl_) & 3][t * 8]);     \
    gld_lds16(kp1 + (size_t)(tl_) * 4096, &k_lds[(tl_) & 3][(t + 256) * 8]); \
    gld_lds16(vp0 + (size_t)(tl_) * 64, &vt_lds[(tl_) % 5][t * 8]);      \
    gld_lds16(vp1 + (size_t)(tl_) * 64, &vt_lds[(tl_) % 5][(t + 256) * 8]); \
  }

  STG(0);
  STG(1);          // 8 instrs outstanding

  f32x16 Oacc[2];
#pragma unroll
  for (int i = 0; i < 16; i++) { Oacc[0][i] = 0.0f; Oacc[1][i] = 0.0f; }
  float lrun = 0.0f;
  bf16x8 pb[4];   // P fragments of the PREVIOUS iteration

  for (int it = 0; it < 32; ++it) {
    int tn = it + 2 <= 31 ? it + 2 : 31;   // tail re-issues tile 31 (same data)
    STG(tn);
    asm volatile("s_waitcnt vmcnt(8)" ::: "memory");   // tile(it) fully landed
    __builtin_amdgcn_s_barrier();                      // sole barrier this iter

    const short* kl = k_lds[it & 3];
    const short* vl = vt_lds[(it + 4) % 5];            // V(it-1)

    // Batch-load ALL fragments (reads pipeline in the LDS unit).
    bf16x8 kfr[8], vfr[8];
#pragma unroll
    for (int i = 0; i < 8; i++) kfr[i] = *(const bf16x8*)&kl[koff[i]];
#pragma unroll
    for (int i = 0; i < 8; i++) vfr[i] = *(const bf16x8*)&vl[koff[i]];

    __builtin_amdgcn_s_setprio(1);
    // S^T = K @ Q^T : lane q = l31
    f32x16 S0 = (f32x16)0.0f, S1 = (f32x16)0.0f;
#pragma unroll
    for (int d4 = 0; d4 < 4; d4++) {
      S0 = MFMA32(kfr[2 * d4], qf[d4], S0);
      S1 = MFMA32(kfr[2 * d4 + 1], qf[d4], S1);
    }
    // O^T += V^T(it-1) @ P(it-1): MFMA pipe, overlaps softmax VALU below
    if (it) {
#pragma unroll
      for (int ks = 0; ks < 4; ks++) {
        Oacc[0] = MFMA32(vfr[2 * ks], pb[ks], Oacc[0]);
        Oacc[1] = MFMA32(vfr[2 * ks + 1], pb[ks], Oacc[1]);
      }
    }
    __builtin_amdgcn_s_setprio(0);

    // softmax(it) with fixed m=0: P = exp2(S), row sum
    float rs0 = 0.0f, rs1 = 0.0f;
#pragma unroll
    for (int i = 0; i < 16; i++) {
      float p0 = ex2(S0[i]);
      float p1 = ex2(S1[i]);
      S0[i] = p0; S1[i] = p1;
      rs0 += p0; rs1 += p1;
    }
    lrun += xhalf_sum(rs0 + rs1);

    // pack P(it) -> pb[0..3] (in-register, no LDS)
#pragma unroll
    for (int ks = 0; ks < 4; ks++) {
      unsigned wA, wB, wC, wD;
      if (ks == 0) {
        wA = cvtpk(S0[0], S0[1]);  wB = cvtpk(S0[2], S0[3]);
        wC = cvtpk(S0[4], S0[5]);  wD = cvtpk(S0[6], S0[7]);
      } else if (ks == 1) {
        wA = cvtpk(S0[8], S0[9]);  wB = cvtpk(S0[10], S0[11]);
        wC = cvtpk(S0[12], S0[13]); wD = cvtpk(S0[14], S0[15]);
      } else if (ks == 2) {
        wA = cvtpk(S1[0], S1[1]);  wB = cvtpk(S1[2], S1[3]);
        wC = cvtpk(S1[4], S1[5]);  wD = cvtpk(S1[6], S1[7]);
      } else {
        wA = cvtpk(S1[8], S1[9]);  wB = cvtpk(S1[10], S1[11]);
        wC = cvtpk(S1[12], S1[13]); wD = cvtpk(S1[14], S1[15]);
      }
      asm volatile("v_permlane32_swap_b32 %0, %1" : "+v"(wA), "+v"(wC));
      asm volatile("v_permlane32_swap_b32 %0, %1" : "+v"(wB), "+v"(wD));
      u32x4 uu; uu.x = wA; uu.y = wB; uu.z = wC; uu.w = wD;
      pb[ks] = __builtin_bit_cast(bf16x8, uu);
    }
    // no end-of-iteration barrier: ring depths (K=4, V=5) make writes at
    // wave-skew<=1 land in slots disjoint from any concurrent reads.
  }
  asm volatile("s_waitcnt vmcnt(0)" ::: "memory");   // drain trailing prefetch
  __builtin_amdgcn_s_barrier();

  // final PV(31): tile 31 -> slot 31 % 5 == 1
  {
    const short* vl = vt_lds[1];
    __builtin_amdgcn_s_setprio(1);
#pragma unroll
    for (int ks = 0; ks < 4; ks++) {
      Oacc[0] = MFMA32(*(const bf16x8*)&vl[koff[2 * ks]], pb[ks], Oacc[0]);
      Oacc[1] = MFMA32(*(const bf16x8*)&vl[koff[2 * ks + 1]], pb[ks], Oacc[1]);
    }
    __builtin_amdgcn_s_setprio(0);
  }

  float rl = 1.0f / lrun;
  if (lane < 32) {
    l_ws[bh * 2048 + qg] = rl;
  }
  // O write: lane holds q=l31, d = dt*32 + g*8 + hi*4 + e  (e contiguous)
#pragma unroll
  for (int dt = 0; dt < 2; dt++)
#pragma unroll
    for (int g = 0; g < 4; g++) {
      short4 o4;
      o4.x = f2bf(Oacc[dt][g * 4 + 0] * rl);
      o4.y = f2bf(Oacc[dt][g * 4 + 1] * rl);
      o4.z = f2bf(Oacc[dt][g * 4 + 2] * rl);
      o4.w = f2bf(Oacc[dt][g * 4 + 3] * rl);
      int d = dt * 32 + g * 8 + hi * 4;
      *(short4*)&o_ws[((size_t)(b * 2048 + qg)) * 1024 + hd * 64 + d] = o4;
    }
}

// 6+7) TAIL: gemm_out (blocks 0..255) || attn2 (blocks 256..1279).
//      attn2 branch: Q-fragment register double-buffer (Q(h+1) issued with
//      stage(h+1), full iteration to land; vmcnt(7) = stage+Q in flight).
__global__ __launch_bounds__(256) void k_tail(
    const short* __restrict__ q_ws, const short* __restrict__ k_ws,
    const float* __restrict__ l_ws, float* __restrict__ out1,
    const short* __restrict__ o_ws, const short* __restrict__ wo_bf,
    const float* __restrict__ bo, const float* __restrict__ x,
    float* __restrict__ out0) {
  __shared__ __align__(16) char smem[3 * 16384 + 3 * 256];  // 49.9 KiB union
  int t = threadIdx.x, lane = t & 63, w = t >> 6;

  if (blockIdx.x < 256) {
    // ---- Output projection + bias + residual (f32 out). BK=32. ----
    short* at = (short*)smem;
    short* bt = (short*)(smem + 8192);
    int wr = w >> 1, wc = w & 1;
    int fo = blockIdx.x;
    int col0 = (fo & 7) * 128, row0 = (fo >> 3) * 128;
    const short* A = o_ws + (size_t)row0 * 1024;
    const short* Bw = wo_bf + (size_t)col0 * 1024;
    f32x4 acc[4][4];
#pragma unroll
    for (int m = 0; m < 4; m++)
#pragma unroll
      for (int n = 0; n < 4; n++) acc[m][n] = (f32x4)0.0f;

    for (int k0 = 0; k0 < 1024; k0 += 32) {
#pragma unroll
      for (int i = 0; i < 2; i++) {
        int c = t + i * 256;
        int r = c >> 2, cc = (c & 3) * 8;
        gld_lds16(A + (size_t)r * 1024 + k0 + cc, &at[c * 8]);
        gld_lds16(Bw + (size_t)r * 1024 + k0 + cc, &bt[c * 8]);
      }
      __syncthreads();
      bf16x8 af[4], bfr[4];
#pragma unroll
      for (int m = 0; m < 4; m++)
        af[m] = *(const bf16x8*)&at[(wr * 64 + m * 16 + (lane & 15)) * 32 + (lane >> 4) * 8];
#pragma unroll
      for (int n = 0; n < 4; n++)
        bfr[n] = *(const bf16x8*)&bt[(wc * 64 + n * 16 + (lane & 15)) * 32 + (lane >> 4) * 8];
#pragma unroll
      for (int m = 0; m < 4; m++)
#pragma unroll
        for (int n = 0; n < 4; n++) acc[m][n] = MFMA(af[m], bfr[n], acc[m][n]);
      __syncthreads();
    }
#pragma unroll
    for (int m = 0; m < 4; m++)
#pragma unroll
      for (int n = 0; n < 4; n++)
#pragma unroll
        for (int r = 0; r < 4; r++) {
          int grow = row0 + wr * 64 + m * 16 + (lane >> 4) * 4 + r;
          int gcol = col0 + wc * 64 + n * 16 + (lane & 15);
          float val = acc[m][n][r] + bo[gcol] + x[(size_t)grow * 1024 + gcol];
          out0[(size_t)grow * 1024 + gcol] = val;
        }
  } else {
    // ---- Mean attention: m=0, K 3-ring, one barrier per head,
    //      Q-fragment register double-buffer. ----
    short* k_lds2 = (short*)smem;                       // 3 x 128*64 shorts
    float* l_lds = (float*)(smem + 49152);              // 3 x 64 floats
    int flat = blockIdx.x - 256;                        // 0..1023
    int mm = (flat & 7) * 128 + (flat >> 3);            // XCD-chunked
    int q0 = (mm & 31) * 64, k2 = ((mm >> 5) & 15) * 128, b = mm >> 9;

    f32x4 pacc[8];
#pragma unroll
    for (int n = 0; n < 8; n++) pacc[n] = (f32x4)0.0f;

    int qrow = q0 + w * 16 + (lane & 15);
    size_t qoff0 = (size_t)qrow * 64 + (lane >> 4) * 8;   // kf=0; kf=1 adds 32
    const short* qb0 = q_ws + (size_t)(b * 16) * (2048 * 64);

#define STAGE2(hh)                                                               \
    {                                                                            \
      int bh_ = b * 16 + (hh);                                                   \
      const short* kb_ = k_ws + (size_t)bh_ * (2048 * 64);                       \
      short* kdst_ = k_lds2 + ((hh) % 3) * (128 * 64);                           \
      _Pragma("unroll")                                                          \
      for (int i = 0; i < 4; i++) {                                              \
        int c = t + i * 256;                                                     \
        int r = c >> 3, j = (c & 7) ^ (r & 7);                                   \
        gld_lds16(kb_ + (size_t)(k2 + r) * 64 + j * 8, &kdst_[c * 8]);           \
      }                                                                          \
      int cc = w * 4 + (t & 63);                                                 \
      if ((t & 63) < 4) {                                                        \
        gld_lds16(&l_ws[(size_t)bh_ * 2048 + q0 + cc * 4],                       \
                  &l_lds[((hh) % 3) * 64 + cc * 4]);                             \
      }                                                                          \
    }

    // Prologue: Q(0) into current regs; stage(0); Q(1) prefetch issues in-loop.
    bf16x8 qc0 = *(const bf16x8*)&qb0[qoff0];
    bf16x8 qc1 = *(const bf16x8*)&qb0[qoff0 + 32];
    STAGE2(0);
    bf16x8 qn0, qn1;
    for (int h = 0; h < 16; ++h) {
      int hn = h < 15 ? h + 1 : 15;
      STAGE2(hn);                                        // 5 vm ops
      qn0 = *(const bf16x8*)&qb0[(size_t)hn * (2048 * 64) + qoff0];      // 2 vm
      qn1 = *(const bf16x8*)&qb0[(size_t)hn * (2048 * 64) + qoff0 + 32];
      asm volatile("s_waitcnt vmcnt(7)" ::: "memory");   // stage(h)+Q(h) done;
      __builtin_amdgcn_s_barrier();                      // stage(h+1)+Q(h+1) fly

      const short* kl = k_lds2 + (h % 3) * (128 * 64);
      f32x4 sc[8];
#pragma unroll
      for (int n = 0; n < 8; n++) sc[n] = (f32x4)0.0f;
#pragma unroll
      for (int kf = 0; kf < 2; kf++)
#pragma unroll
        for (int n = 0; n < 8; n++) {
          int row = n * 16 + (lane & 15);
          bf16x8 kfr = *(const bf16x8*)&kl[row * 64 + (((kf * 4 + (lane >> 4)) ^ (row & 7)) * 8)];
          sc[n] = MFMA(kf == 0 ? qc0 : qc1, kfr, sc[n]);
        }
      f32x4 lh = *(const f32x4*)&l_lds[(h % 3) * 64 + w * 16 + (lane >> 4) * 4];
#pragma unroll
      for (int n = 0; n < 8; n++)
#pragma unroll
        for (int r = 0; r < 4; r++)
          pacc[n][r] += ex2(sc[n][r]) * lh[r];
      qc0 = qn0; qc1 = qn1;                              // rotate Q dbuf
      // no end barrier: 3-ring write slot (h+2)%3 != read slot h%3 at skew<=1.
    }

#pragma unroll
    for (int n = 0; n < 8; n++)
#pragma unroll
      for (int r = 0; r < 4; r++) {
        int q = q0 + w * 16 + (lane >> 4) * 4 + r;
        int k = k2 + n * 16 + (lane & 15);
        out1[((size_t)b * 2048 + q) * 2048 + k] = pacc[n][r] * 0.0625f;
      }
  }
}

extern "C" void kernel_launch(void* const* d_in, const int* in_sizes, int n_in,
                              void* d_out, int out_size, void* d_ws, size_t ws_size,
                              hipStream_t stream) {
  (void)in_sizes; (void)n_in; (void)out_size; (void)ws_size;
  const float* x   = (const float*)d_in[0];
  const float* Wq  = (const float*)d_in[1];
  const float* bq  = (const float*)d_in[2];
  const float* Wk  = (const float*)d_in[3];
  const float* bk  = (const float*)d_in[4];
  const float* Wv  = (const float*)d_in[5];
  const float* bv  = (const float*)d_in[6];
  const float* Wo  = (const float*)d_in[7];
  const float* bo  = (const float*)d_in[8];
  const float* lng = (const float*)d_in[9];
  const float* lnb = (const float*)d_in[10];
  float* out0 = (float*)d_out;
  float* out1 = out0 + (size_t)2 * 2048 * 1024;

  char* ws = (char*)d_ws;
  short* xn    = (short*)(ws);                 // 8 MiB
  short* q_ws  = (short*)(ws + 8388608);       // 8 MiB
  short* k_ws  = (short*)(ws + 16777216);      // 8 MiB
  short* o_ws  = (short*)(ws + 25165824);      // 8 MiB (attention output O)
  short* vt_ws = (short*)(ws + 33554432);      // 8 MiB (V^T from QKV GEMM)
  short* wbf   = (short*)(ws + 41943040);      // 8 MiB (Wq,Wk,Wv,Wo bf16)
  float* l_ws  = (float*)(ws + 50331648);      // 256 KiB

  k_cvtw_ln<<<8192, 256, 0, stream>>>(Wq, Wk, Wv, Wo, wbf, x, lng, lnb, xn);
  k_gemm_qkv<<<dim3(4, 16, 3), 512, 0, stream>>>(xn, wbf, bq, bk, bv, q_ws, k_ws, vt_ws);
  k_attn1<<<dim3(16, 16, 2), 256, 0, stream>>>(q_ws, k_ws, vt_ws, o_ws, l_ws);
  k_tail<<<1280, 256, 0, stream>>>(q_ws, k_ws, l_ws, out1,
                                   o_ws, wbf + (size_t)3 * 1024 * 1024, bo, x, out0);
}